// Round 6
// baseline (481.891 us; speedup 1.0000x reference)
//
#include <hip/hip_runtime.h>

#define EPSI 1e-5f

__device__ __forceinline__ float lrelu(float x) { return x > 0.f ? x : 0.01f * x; }

// Block-wide sum of (a,b). blockDim.x == 256. Result broadcast to all threads.
__device__ __forceinline__ float2 block_reduce_sum2(float a, float b) {
    #pragma unroll
    for (int off = 1; off < 64; off <<= 1) {
        a += __shfl_xor(a, off, 64);
        b += __shfl_xor(b, off, 64);
    }
    __shared__ float lds[8];
    const int t = threadIdx.x;
    if ((t & 63) == 0) { lds[2 * (t >> 6)] = a; lds[2 * (t >> 6) + 1] = b; }
    __syncthreads();
    a = lds[0] + lds[2] + lds[4] + lds[6];
    b = lds[1] + lds[3] + lds[5] + lds[7];
    return make_float2(a, b);
}

// ---------------- K1: conv1(3->16) + IN + lrelu, ALL co per block ----------------
// grid: B=256 blocks, 1024 threads, 4 px/thread, acc[16][4] in VGPRs.
// launch_bounds(1024,4): 1 block/CU, VGPR cap 128 (512/4). R5 lesson: without the
// 2nd arg the compiler caps at 64 and spills the 64-float accumulator to scratch.
__global__ __launch_bounds__(1024, 4) void k1_conv_in(const float* __restrict__ x,
                                                      const float* __restrict__ w1,
                                                      float* __restrict__ h1) {
    const int n = blockIdx.x;
    const int t = threadIdx.x;
    __shared__ float wl[192];        // [co][ic][2][2], w1 layout verbatim
    __shared__ float red[16][16][2]; // [wave][co][s1/s2]
    __shared__ float msc[16][2];     // [co][mean/scale]
    if (t < 192) wl[t] = w1[t];
    __syncthreads();
    const float* xn = x + (size_t)n * 49152;
    float acc[16][4];
    #pragma unroll
    for (int j = 0; j < 16; ++j)
        #pragma unroll
        for (int q = 0; q < 4; ++q) acc[j][q] = 0.f;
    #pragma unroll 1
    for (int ic = 0; ic < 3; ++ic) {
        const float* p = xn + ic * 16384;
        float2 v0[4], v1[4];
        #pragma unroll
        for (int q = 0; q < 4; ++q) {
            const int idx = t + 1024 * q;
            const int oy = idx >> 6, ox = idx & 63;
            v0[q] = ((const float2*)(p + (2 * oy) * 128))[ox];
            v1[q] = ((const float2*)(p + (2 * oy + 1) * 128))[ox];
        }
        #pragma unroll
        for (int j = 0; j < 16; ++j) {
            const float4 wv = *(const float4*)&wl[j * 12 + ic * 4];
            #pragma unroll
            for (int q = 0; q < 4; ++q)
                acc[j][q] += v0[q].x * wv.x + v0[q].y * wv.y + v1[q].x * wv.z + v1[q].y * wv.w;
        }
    }
    const int w = t >> 6, l = t & 63;
    #pragma unroll
    for (int j = 0; j < 16; ++j) {
        float s1 = acc[j][0] + acc[j][1] + acc[j][2] + acc[j][3];
        float s2 = acc[j][0] * acc[j][0] + acc[j][1] * acc[j][1] +
                   acc[j][2] * acc[j][2] + acc[j][3] * acc[j][3];
        #pragma unroll
        for (int off = 1; off < 64; off <<= 1) {
            s1 += __shfl_xor(s1, off, 64);
            s2 += __shfl_xor(s2, off, 64);
        }
        if (l == 0) { red[w][j][0] = s1; red[w][j][1] = s2; }
    }
    __syncthreads();
    if (t < 16) {
        float s1 = 0.f, s2 = 0.f;
        #pragma unroll
        for (int ww = 0; ww < 16; ++ww) { s1 += red[ww][t][0]; s2 += red[ww][t][1]; }
        const float mean = s1 * (1.f / 4096.f);
        const float var = s2 * (1.f / 4096.f) - mean * mean;
        msc[t][0] = mean; msc[t][1] = rsqrtf(var + EPSI);
    }
    __syncthreads();
    float* on = h1 + (size_t)n * 65536;
    #pragma unroll
    for (int j = 0; j < 16; ++j) {
        const float mean = msc[j][0], sc = msc[j][1];
        #pragma unroll
        for (int q = 0; q < 4; ++q)
            on[j * 4096 + t + 1024 * q] = lrelu((acc[j][q] - mean) * sc);
    }
}

// ---------------- K2: conv2(16->32) + IN + lrelu, ALL co per block ---------------
// grid: B=256 blocks, 512 threads, 2 px/thread, acc[32][2] in VGPRs.
// launch_bounds(512,4): 2 blocks/CU, VGPR cap 128. unroll 1 on ic (hoisting guard).
__global__ __launch_bounds__(512, 4) void k2_conv_in(const float* __restrict__ h1,
                                                     const float* __restrict__ w2,
                                                     float* __restrict__ h2) {
    const int n = blockIdx.x;
    const int t = threadIdx.x;
    __shared__ float wl[32 * 16 * 4]; // 8KB: [co][ic][2][2]
    __shared__ float red[8][32][2];
    __shared__ float msc[32][2];
    for (int i = t; i < 2048; i += 512) {
        const int co = i >> 6, rest = i & 63;          // 64 floats per co (16 ic * 4)
        wl[i] = w2[(size_t)co * 144 + rest];           // w2 co-stride 36*4=144; ic<16 used
    }
    __syncthreads();
    const float* h1n = h1 + (size_t)n * 65536;
    float acc[32][2];
    #pragma unroll
    for (int j = 0; j < 32; ++j) { acc[j][0] = 0.f; acc[j][1] = 0.f; }
    #pragma unroll 1
    for (int ic = 0; ic < 16; ++ic) {
        const float* p = h1n + ic * 4096;
        float2 v0[2], v1[2];
        #pragma unroll
        for (int q = 0; q < 2; ++q) {
            const int idx = t + 512 * q;
            const int oy = idx >> 5, ox = idx & 31;
            v0[q] = ((const float2*)(p + (2 * oy) * 64))[ox];
            v1[q] = ((const float2*)(p + (2 * oy + 1) * 64))[ox];
        }
        #pragma unroll
        for (int j = 0; j < 32; ++j) {
            const float4 wv = *(const float4*)&wl[(j * 16 + ic) * 4];
            #pragma unroll
            for (int q = 0; q < 2; ++q)
                acc[j][q] += v0[q].x * wv.x + v0[q].y * wv.y + v1[q].x * wv.z + v1[q].y * wv.w;
        }
    }
    const int w = t >> 6, l = t & 63;
    #pragma unroll
    for (int j = 0; j < 32; ++j) {
        float s1 = acc[j][0] + acc[j][1];
        float s2 = acc[j][0] * acc[j][0] + acc[j][1] * acc[j][1];
        #pragma unroll
        for (int off = 1; off < 64; off <<= 1) {
            s1 += __shfl_xor(s1, off, 64);
            s2 += __shfl_xor(s2, off, 64);
        }
        if (l == 0) { red[w][j][0] = s1; red[w][j][1] = s2; }
    }
    __syncthreads();
    if (t < 32) {
        float s1 = 0.f, s2 = 0.f;
        #pragma unroll
        for (int ww = 0; ww < 8; ++ww) { s1 += red[ww][t][0]; s2 += red[ww][t][1]; }
        const float mean = s1 * (1.f / 1024.f);
        const float var = s2 * (1.f / 1024.f) - mean * mean;
        msc[t][0] = mean; msc[t][1] = rsqrtf(var + EPSI);
    }
    __syncthreads();
    float* on = h2 + (size_t)n * 32768;
    #pragma unroll
    for (int j = 0; j < 32; ++j) {
        const float mean = msc[j][0], sc = msc[j][1];
        #pragma unroll
        for (int q = 0; q < 2; ++q)
            on[j * 1024 + t + 512 * q] = lrelu((acc[j][q] - mean) * sc);
    }
}

// ---------------- K3: conv3(32->64) + IN + lrelu, 2n x 16co per block ------------
// grid: 512 blocks, 256 threads. acc[16][2] in VGPRs. launch_bounds(256,4): cap 128.
__global__ __launch_bounds__(256, 4) void k3_conv_in(const float* __restrict__ h2,
                                                     const float* __restrict__ w3,
                                                     float* __restrict__ h3) {
    const int n0 = (blockIdx.x >> 2) * 2, cg = blockIdx.x & 3;
    const int t = threadIdx.x;
    __shared__ float wl[16 * 32 * 4];  // 8KB: [co_local][ic][2][2]
    __shared__ float red[4][16][2][2]; // [wave][co][n][s1/s2]
    for (int i = t; i < 2048; i += 256)
        wl[i] = w3[(size_t)cg * 2048 + i];   // 16 co * 128, contiguous
    __syncthreads();
    const int oy = t >> 4, ox = t & 15;
    float acc[16][2];
    #pragma unroll
    for (int j = 0; j < 16; ++j) { acc[j][0] = 0.f; acc[j][1] = 0.f; }
    #pragma unroll 1
    for (int ic = 0; ic < 32; ++ic) {
        float2 v0[2], v1[2];
        #pragma unroll
        for (int nn = 0; nn < 2; ++nn) {
            const float* p = h2 + ((size_t)(n0 + nn) * 32 + ic) * 1024 + (2 * oy) * 32;
            v0[nn] = ((const float2*)p)[ox];
            v1[nn] = ((const float2*)(p + 32))[ox];
        }
        #pragma unroll
        for (int j = 0; j < 16; ++j) {
            const float4 wv = *(const float4*)&wl[(j * 32 + ic) * 4];
            #pragma unroll
            for (int nn = 0; nn < 2; ++nn)
                acc[j][nn] += v0[nn].x * wv.x + v0[nn].y * wv.y + v1[nn].x * wv.z + v1[nn].y * wv.w;
        }
    }
    const int w = t >> 6, l = t & 63;
    #pragma unroll
    for (int j = 0; j < 16; ++j) {
        #pragma unroll
        for (int nn = 0; nn < 2; ++nn) {
            float s1 = acc[j][nn], s2 = acc[j][nn] * acc[j][nn];
            #pragma unroll
            for (int off = 1; off < 64; off <<= 1) {
                s1 += __shfl_xor(s1, off, 64);
                s2 += __shfl_xor(s2, off, 64);
            }
            if (l == 0) { red[w][j][nn][0] = s1; red[w][j][nn][1] = s2; }
        }
    }
    __syncthreads();
    #pragma unroll
    for (int j = 0; j < 16; ++j) {
        #pragma unroll
        for (int nn = 0; nn < 2; ++nn) {
            const float s1 = red[0][j][nn][0] + red[1][j][nn][0] + red[2][j][nn][0] + red[3][j][nn][0];
            const float s2 = red[0][j][nn][1] + red[1][j][nn][1] + red[2][j][nn][1] + red[3][j][nn][1];
            const float mean = s1 * (1.f / 256.f);
            const float var = s2 * (1.f / 256.f) - mean * mean;
            const float sc = rsqrtf(var + EPSI);
            h3[((size_t)(n0 + nn) * 64 + cg * 16 + j) * 256 + t] = lrelu((acc[j][nn] - mean) * sc);
        }
    }
}

// ---------------- K4: conv4(64->128) + IN + lrelu, 4n x 32co per block -----------
// grid: 256 blocks, 256 threads. acc[8][4] in VGPRs. launch_bounds(256,4): cap 128.
__global__ __launch_bounds__(256, 4) void k4_conv_in(const float* __restrict__ h3,
                                                     const float* __restrict__ w4,
                                                     float* __restrict__ h4) {
    const int n0 = (blockIdx.x >> 2) * 4, cg = blockIdx.x & 3;
    const int t = threadIdx.x;
    __shared__ float wl[32 * 64 * 4];  // 32KB: [co_local][ic][2][2]
    for (int i = t; i < 8192; i += 256)
        wl[i] = w4[(size_t)cg * 8192 + i];
    __syncthreads();
    const int w = t >> 6, l = t & 63;
    const int oy = l >> 3, ox = l & 7;
    float acc[8][4];
    #pragma unroll
    for (int jj = 0; jj < 8; ++jj)
        #pragma unroll
        for (int nn = 0; nn < 4; ++nn) acc[jj][nn] = 0.f;
    #pragma unroll 1
    for (int ic = 0; ic < 64; ++ic) {
        float2 v0[4], v1[4];
        #pragma unroll
        for (int nn = 0; nn < 4; ++nn) {
            const float* p = h3 + ((size_t)(n0 + nn) * 64 + ic) * 256 + (2 * oy) * 16;
            v0[nn] = ((const float2*)p)[ox];
            v1[nn] = ((const float2*)(p + 16))[ox];
        }
        #pragma unroll
        for (int jj = 0; jj < 8; ++jj) {
            const float4 wv = *(const float4*)&wl[((w * 8 + jj) * 64 + ic) * 4];
            #pragma unroll
            for (int nn = 0; nn < 4; ++nn)
                acc[jj][nn] += v0[nn].x * wv.x + v0[nn].y * wv.y + v1[nn].x * wv.z + v1[nn].y * wv.w;
        }
    }
    #pragma unroll
    for (int jj = 0; jj < 8; ++jj) {
        #pragma unroll
        for (int nn = 0; nn < 4; ++nn) {
            float s1 = acc[jj][nn], s2 = acc[jj][nn] * acc[jj][nn];
            #pragma unroll
            for (int off = 1; off < 64; off <<= 1) {
                s1 += __shfl_xor(s1, off, 64);
                s2 += __shfl_xor(s2, off, 64);
            }
            const float mean = s1 * (1.f / 64.f);
            const float var = s2 * (1.f / 64.f) - mean * mean;
            const float sc = rsqrtf(var + EPSI);
            const int co = cg * 32 + w * 8 + jj;
            h4[((size_t)(n0 + nn) * 128 + co) * 64 + l] = lrelu((acc[jj][nn] - mean) * sc);
        }
    }
}

// ---------------- K5: FC1 split-K GEMM, partials to workspace --------------------
// C[256,1024] = A[256,8192] x W[1024,8192]^T. BM=BN=64, SK=16 (512 K each), BK=32.
// grid = 64 tiles * 16 sk = 1024 blocks, 256 threads, 4x4 acc/thread.
__global__ __launch_bounds__(256) void k5_fc1(const float* __restrict__ A,
                                              const float* __restrict__ W,
                                              float* __restrict__ Cp) {
    __shared__ float As[32][64];  // [kk][m], m-quad XOR-swizzled
    __shared__ float Bs[32][64];  // [kk][n], n-quad XOR-swizzled
    const int t = threadIdx.x;
    const int sk = blockIdx.x >> 6;
    const int tile = blockIdx.x & 63;
    const int mt = tile >> 4, nt = tile & 15;
    const int m0 = mt * 64, n0 = nt * 64;
    const int tx = t & 15;    // n quad 4*tx
    const int ty = t >> 4;    // m quad 4*ty
    const int lr = t >> 2, lq = t & 3;  // load: row, k-quad
    float acc[4][4] = {};
    const int kbeg = sk * 512;
    for (int k0 = kbeg; k0 < kbeg + 512; k0 += 32) {
        const float4 av0 = *(const float4*)(A + (size_t)(m0 + lr) * 8192 + k0 + 4 * lq);
        const float4 av1 = *(const float4*)(A + (size_t)(m0 + lr) * 8192 + k0 + 16 + 4 * lq);
        const float4 bv0 = *(const float4*)(W + (size_t)(n0 + lr) * 8192 + k0 + 4 * lq);
        const float4 bv1 = *(const float4*)(W + (size_t)(n0 + lr) * 8192 + k0 + 16 + 4 * lq);
        __syncthreads();
        {
            const float a0[4] = {av0.x, av0.y, av0.z, av0.w};
            const float a1[4] = {av1.x, av1.y, av1.z, av1.w};
            const float b0[4] = {bv0.x, bv0.y, bv0.z, bv0.w};
            const float b1[4] = {bv1.x, bv1.y, bv1.z, bv1.w};
            const int q = lr >> 2, r = lr & 3;
            #pragma unroll
            for (int j = 0; j < 4; ++j) {
                const int kkA = 4 * lq + j, kkB = kkA + 16;
                As[kkA][(((q ^ kkA) & 15) << 2) | r] = a0[j];
                As[kkB][(((q ^ kkB) & 15) << 2) | r] = a1[j];
                Bs[kkA][(((q ^ kkA) & 15) << 2) | r] = b0[j];
                Bs[kkB][(((q ^ kkB) & 15) << 2) | r] = b1[j];
            }
        }
        __syncthreads();
        #pragma unroll
        for (int kk = 0; kk < 32; ++kk) {
            const float4 a4 = *(const float4*)&As[kk][((ty ^ kk) & 15) << 2];
            const float4 b4 = *(const float4*)&Bs[kk][((tx ^ kk) & 15) << 2];
            const float a[4] = {a4.x, a4.y, a4.z, a4.w};
            const float b[4] = {b4.x, b4.y, b4.z, b4.w};
            #pragma unroll
            for (int i = 0; i < 4; ++i)
                #pragma unroll
                for (int j = 0; j < 4; ++j)
                    acc[i][j] += a[i] * b[j];
        }
    }
    #pragma unroll
    for (int i = 0; i < 4; ++i) {
        const int m = m0 + 4 * ty + i;
        float4 v = make_float4(acc[i][0], acc[i][1], acc[i][2], acc[i][3]);
        *(float4*)(Cp + ((size_t)sk * 256 + m) * 1024 + n0 + 4 * tx) = v;
    }
}

// ---------------- R5: reduce split-K partials + bias + lrelu ---------------------
__global__ __launch_bounds__(256) void r5_reduce(const float* __restrict__ Cp,
                                                 const float* __restrict__ bias,
                                                 float* __restrict__ h5) {
    const int gid = blockIdx.x * 256 + threadIdx.x;  // 256*1024 total
    const int m = gid >> 10, nn = gid & 1023;
    float s = 0.f;
    #pragma unroll
    for (int sk = 0; sk < 16; ++sk)
        s += Cp[((size_t)sk * 256 + m) * 1024 + nn];
    h5[gid] = lrelu(s + bias[nn]);
}

// ---------------- K6: FC2 [256,1024]x[1,1024]^T + bias ---------------------------
__global__ __launch_bounds__(256) void k6_fc2(const float* __restrict__ h5,
                                              const float* __restrict__ w,
                                              const float* __restrict__ b,
                                              float* __restrict__ out) {
    const int n = blockIdx.x, t = threadIdx.x;
    const float* r = h5 + (size_t)n * 1024;
    float s = 0.f;
    #pragma unroll
    for (int i = 0; i < 4; ++i) s += r[t + 256 * i] * w[t + 256 * i];
    const float2 red = block_reduce_sum2(s, 0.f);
    if (t == 0) out[n] = red.x + b[0];
}

extern "C" void kernel_launch(void* const* d_in, const int* in_sizes, int n_in,
                              void* d_out, int out_size, void* d_ws, size_t ws_size,
                              hipStream_t stream) {
    (void)in_sizes; (void)n_in; (void)out_size; (void)ws_size;
    const float* x    = (const float*)d_in[0];
    // labels (d_in[1]) and conv biases (d_in[3,5,7,9]) cancel exactly under InstanceNorm
    const float* w1   = (const float*)d_in[2];
    const float* w2   = (const float*)d_in[4];
    const float* w3   = (const float*)d_in[6];
    const float* w4   = (const float*)d_in[8];
    const float* fcw1 = (const float*)d_in[10];
    const float* fcb1 = (const float*)d_in[11];
    const float* fcw2 = (const float*)d_in[12];
    const float* fcb2 = (const float*)d_in[13];
    float* out = (float*)d_out;
    float* bufA = (float*)d_ws;          // 16,777,216 floats (67.1 MB)
    float* bufB = bufA + 16777216;       //  8,388,608 floats (33.5 MB)
    float* h1 = bufA;                    // 16.7M floats
    float* h2 = bufB;                    // 8.4M used
    float* h3 = bufA;                    // h1 dead
    float* h4 = bufB;                    // h2 dead
    float* Cp = bufA;                    // h3 dead at k5; 4.2M floats
    float* h5 = bufA + 4194304;          // 262144 floats
    k1_conv_in<<<256, 1024, 0, stream>>>(x, w1, h1);
    k2_conv_in<<<256, 512, 0, stream>>>(h1, w2, h2);
    k3_conv_in<<<512, 256, 0, stream>>>(h2, w3, h3);
    k4_conv_in<<<256, 256, 0, stream>>>(h3, w4, h4);
    k5_fc1<<<1024, 256, 0, stream>>>(h4, fcw1, Cp);
    r5_reduce<<<1024, 256, 0, stream>>>(Cp, fcb1, h5);
    k6_fc2<<<256, 256, 0, stream>>>(h5, fcw2, fcb2, out);
}

// Round 7
// 216.203 us; speedup vs baseline: 2.2289x; 2.2289x over previous
//
#include <hip/hip_runtime.h>

#define EPSI 1e-5f

__device__ __forceinline__ float lrelu(float x) { return x > 0.f ? x : 0.01f * x; }

// Block-wide sum of (a,b). blockDim.x == 256. Result broadcast to all threads.
__device__ __forceinline__ float2 block_reduce_sum2(float a, float b) {
    #pragma unroll
    for (int off = 1; off < 64; off <<= 1) {
        a += __shfl_xor(a, off, 64);
        b += __shfl_xor(b, off, 64);
    }
    __shared__ float lds[8];
    const int t = threadIdx.x;
    if ((t & 63) == 0) { lds[2 * (t >> 6)] = a; lds[2 * (t >> 6) + 1] = b; }
    __syncthreads();
    a = lds[0] + lds[2] + lds[4] + lds[6];
    b = lds[1] + lds[3] + lds[5] + lds[7];
    return make_float2(a, b);
}

// ---------------- K1: conv1(3->16) + IN + lrelu, ALL co per block ----------------
// grid: B=256 blocks, 1024 threads, 4 px/thread, acc[16][4] in VGPRs.
// launch_bounds(1024,1): 2nd arg = min BLOCKS/CU on this toolchain (R6 decode:
// (512,4) gave cap 64 = 32 waves/CU). 1 block x 16 waves -> cap 128 VGPR.
// Weights read from global with block-uniform indices -> s_load into SGPRs
// (no VGPR pressure, no LDS-read hoisting hazard).
__global__ __launch_bounds__(1024, 1) void k1_conv_in(const float* __restrict__ x,
                                                      const float* __restrict__ w1,
                                                      float* __restrict__ h1) {
    const int n = blockIdx.x;
    const int t = threadIdx.x;
    __shared__ float red[16][16][2]; // [wave][co][s1/s2]
    __shared__ float msc[16][2];     // [co][mean/scale]
    const float* xn = x + (size_t)n * 49152;
    float acc[16][4];
    #pragma unroll
    for (int j = 0; j < 16; ++j)
        #pragma unroll
        for (int q = 0; q < 4; ++q) acc[j][q] = 0.f;
    #pragma unroll 1
    for (int ic = 0; ic < 3; ++ic) {
        const float* p = xn + ic * 16384;
        float2 v0[4], v1[4];
        #pragma unroll
        for (int q = 0; q < 4; ++q) {
            const int idx = t + 1024 * q;
            const int oy = idx >> 6, ox = idx & 63;
            v0[q] = ((const float2*)(p + (2 * oy) * 128))[ox];
            v1[q] = ((const float2*)(p + (2 * oy + 1) * 128))[ox];
        }
        #pragma unroll
        for (int j = 0; j < 16; ++j) {
            const float4 wv = *(const float4*)(w1 + j * 12 + ic * 4);  // uniform -> SGPR
            #pragma unroll
            for (int q = 0; q < 4; ++q)
                acc[j][q] += v0[q].x * wv.x + v0[q].y * wv.y + v1[q].x * wv.z + v1[q].y * wv.w;
        }
    }
    const int w = t >> 6, l = t & 63;
    #pragma unroll
    for (int j = 0; j < 16; ++j) {
        float s1 = acc[j][0] + acc[j][1] + acc[j][2] + acc[j][3];
        float s2 = acc[j][0] * acc[j][0] + acc[j][1] * acc[j][1] +
                   acc[j][2] * acc[j][2] + acc[j][3] * acc[j][3];
        #pragma unroll
        for (int off = 1; off < 64; off <<= 1) {
            s1 += __shfl_xor(s1, off, 64);
            s2 += __shfl_xor(s2, off, 64);
        }
        if (l == 0) { red[w][j][0] = s1; red[w][j][1] = s2; }
    }
    __syncthreads();
    if (t < 16) {
        float s1 = 0.f, s2 = 0.f;
        #pragma unroll
        for (int ww = 0; ww < 16; ++ww) { s1 += red[ww][t][0]; s2 += red[ww][t][1]; }
        const float mean = s1 * (1.f / 4096.f);
        const float var = s2 * (1.f / 4096.f) - mean * mean;
        msc[t][0] = mean; msc[t][1] = rsqrtf(var + EPSI);
    }
    __syncthreads();
    float* on = h1 + (size_t)n * 65536;
    #pragma unroll
    for (int j = 0; j < 16; ++j) {
        const float mean = msc[j][0], sc = msc[j][1];
        #pragma unroll
        for (int q = 0; q < 4; ++q)
            on[j * 4096 + t + 1024 * q] = lrelu((acc[j][q] - mean) * sc);
    }
}

// ---------------- K2: conv2(16->32) + IN + lrelu, ALL co per block ---------------
// grid: B=256 blocks, 512 threads, 2 px/thread, acc[32][2] in VGPRs.
// launch_bounds(512,2): 2 blocks x 8 waves = 16 waves/CU -> cap 128 VGPR.
// Weights via uniform global reads (SGPR), so live VGPRs = 64 acc + 8 v + addr.
__global__ __launch_bounds__(512, 2) void k2_conv_in(const float* __restrict__ h1,
                                                     const float* __restrict__ w2,
                                                     float* __restrict__ h2) {
    const int n = blockIdx.x;
    const int t = threadIdx.x;
    __shared__ float red[8][32][2];
    __shared__ float msc[32][2];
    const float* h1n = h1 + (size_t)n * 65536;
    float acc[32][2];
    #pragma unroll
    for (int j = 0; j < 32; ++j) { acc[j][0] = 0.f; acc[j][1] = 0.f; }
    #pragma unroll 1
    for (int ic = 0; ic < 16; ++ic) {
        const float* p = h1n + ic * 4096;
        float2 v0[2], v1[2];
        #pragma unroll
        for (int q = 0; q < 2; ++q) {
            const int idx = t + 512 * q;
            const int oy = idx >> 5, ox = idx & 31;
            v0[q] = ((const float2*)(p + (2 * oy) * 64))[ox];
            v1[q] = ((const float2*)(p + (2 * oy + 1) * 64))[ox];
        }
        #pragma unroll
        for (int j = 0; j < 32; ++j) {
            const float4 wv = *(const float4*)(w2 + j * 144 + ic * 4);  // uniform -> SGPR
            #pragma unroll
            for (int q = 0; q < 2; ++q)
                acc[j][q] += v0[q].x * wv.x + v0[q].y * wv.y + v1[q].x * wv.z + v1[q].y * wv.w;
        }
    }
    const int w = t >> 6, l = t & 63;
    #pragma unroll
    for (int j = 0; j < 32; ++j) {
        float s1 = acc[j][0] + acc[j][1];
        float s2 = acc[j][0] * acc[j][0] + acc[j][1] * acc[j][1];
        #pragma unroll
        for (int off = 1; off < 64; off <<= 1) {
            s1 += __shfl_xor(s1, off, 64);
            s2 += __shfl_xor(s2, off, 64);
        }
        if (l == 0) { red[w][j][0] = s1; red[w][j][1] = s2; }
    }
    __syncthreads();
    if (t < 32) {
        float s1 = 0.f, s2 = 0.f;
        #pragma unroll
        for (int ww = 0; ww < 8; ++ww) { s1 += red[ww][t][0]; s2 += red[ww][t][1]; }
        const float mean = s1 * (1.f / 1024.f);
        const float var = s2 * (1.f / 1024.f) - mean * mean;
        msc[t][0] = mean; msc[t][1] = rsqrtf(var + EPSI);
    }
    __syncthreads();
    float* on = h2 + (size_t)n * 32768;
    #pragma unroll
    for (int j = 0; j < 32; ++j) {
        const float mean = msc[j][0], sc = msc[j][1];
        #pragma unroll
        for (int q = 0; q < 2; ++q)
            on[j * 1024 + t + 512 * q] = lrelu((acc[j][q] - mean) * sc);
    }
}

// ---------------- K3: conv3(32->64) + IN + lrelu, 2n x 16co per block ------------
// grid: 512 blocks, 256 threads. acc[16][2]=32 + 8 v regs fits default cap.
// Weights via uniform global reads (SGPR).
__global__ __launch_bounds__(256, 2) void k3_conv_in(const float* __restrict__ h2,
                                                     const float* __restrict__ w3,
                                                     float* __restrict__ h3) {
    const int n0 = (blockIdx.x >> 2) * 2, cg = blockIdx.x & 3;
    const int t = threadIdx.x;
    __shared__ float red[4][16][2][2]; // [wave][co][n][s1/s2]
    const int oy = t >> 4, ox = t & 15;
    float acc[16][2];
    #pragma unroll
    for (int j = 0; j < 16; ++j) { acc[j][0] = 0.f; acc[j][1] = 0.f; }
    #pragma unroll 1
    for (int ic = 0; ic < 32; ++ic) {
        float2 v0[2], v1[2];
        #pragma unroll
        for (int nn = 0; nn < 2; ++nn) {
            const float* p = h2 + ((size_t)(n0 + nn) * 32 + ic) * 1024 + (2 * oy) * 32;
            v0[nn] = ((const float2*)p)[ox];
            v1[nn] = ((const float2*)(p + 32))[ox];
        }
        #pragma unroll
        for (int j = 0; j < 16; ++j) {
            const float4 wv = *(const float4*)(w3 + (size_t)(cg * 16 + j) * 128 + ic * 4);
            #pragma unroll
            for (int nn = 0; nn < 2; ++nn)
                acc[j][nn] += v0[nn].x * wv.x + v0[nn].y * wv.y + v1[nn].x * wv.z + v1[nn].y * wv.w;
        }
    }
    const int w = t >> 6, l = t & 63;
    #pragma unroll
    for (int j = 0; j < 16; ++j) {
        #pragma unroll
        for (int nn = 0; nn < 2; ++nn) {
            float s1 = acc[j][nn], s2 = acc[j][nn] * acc[j][nn];
            #pragma unroll
            for (int off = 1; off < 64; off <<= 1) {
                s1 += __shfl_xor(s1, off, 64);
                s2 += __shfl_xor(s2, off, 64);
            }
            if (l == 0) { red[w][j][nn][0] = s1; red[w][j][nn][1] = s2; }
        }
    }
    __syncthreads();
    #pragma unroll
    for (int j = 0; j < 16; ++j) {
        #pragma unroll
        for (int nn = 0; nn < 2; ++nn) {
            const float s1 = red[0][j][nn][0] + red[1][j][nn][0] + red[2][j][nn][0] + red[3][j][nn][0];
            const float s2 = red[0][j][nn][1] + red[1][j][nn][1] + red[2][j][nn][1] + red[3][j][nn][1];
            const float mean = s1 * (1.f / 256.f);
            const float var = s2 * (1.f / 256.f) - mean * mean;
            const float sc = rsqrtf(var + EPSI);
            h3[((size_t)(n0 + nn) * 64 + cg * 16 + j) * 256 + t] = lrelu((acc[j][nn] - mean) * sc);
        }
    }
}

// ---------------- K4: conv4(64->128) + IN + lrelu, 4n x 32co per block -----------
// grid: 256 blocks, 256 threads. Wave w: co octet; readfirstlane makes w provably
// wave-uniform so weight reads become s_loads (SGPR).
__global__ __launch_bounds__(256, 2) void k4_conv_in(const float* __restrict__ h3,
                                                     const float* __restrict__ w4,
                                                     float* __restrict__ h4) {
    const int n0 = (blockIdx.x >> 2) * 4, cg = blockIdx.x & 3;
    const int t = threadIdx.x;
    const int w = __builtin_amdgcn_readfirstlane(t >> 6);
    const int l = t & 63;
    const int oy = l >> 3, ox = l & 7;
    const float* wbase = w4 + (size_t)(cg * 32 + w * 8) * 256;
    float acc[8][4];
    #pragma unroll
    for (int jj = 0; jj < 8; ++jj)
        #pragma unroll
        for (int nn = 0; nn < 4; ++nn) acc[jj][nn] = 0.f;
    #pragma unroll 1
    for (int ic = 0; ic < 64; ++ic) {
        float2 v0[4], v1[4];
        #pragma unroll
        for (int nn = 0; nn < 4; ++nn) {
            const float* p = h3 + ((size_t)(n0 + nn) * 64 + ic) * 256 + (2 * oy) * 16;
            v0[nn] = ((const float2*)p)[ox];
            v1[nn] = ((const float2*)(p + 16))[ox];
        }
        #pragma unroll
        for (int jj = 0; jj < 8; ++jj) {
            const float4 wv = *(const float4*)(wbase + jj * 256 + ic * 4);  // wave-uniform -> SGPR
            #pragma unroll
            for (int nn = 0; nn < 4; ++nn)
                acc[jj][nn] += v0[nn].x * wv.x + v0[nn].y * wv.y + v1[nn].x * wv.z + v1[nn].y * wv.w;
        }
    }
    #pragma unroll
    for (int jj = 0; jj < 8; ++jj) {
        #pragma unroll
        for (int nn = 0; nn < 4; ++nn) {
            float s1 = acc[jj][nn], s2 = acc[jj][nn] * acc[jj][nn];
            #pragma unroll
            for (int off = 1; off < 64; off <<= 1) {
                s1 += __shfl_xor(s1, off, 64);
                s2 += __shfl_xor(s2, off, 64);
            }
            const float mean = s1 * (1.f / 64.f);
            const float var = s2 * (1.f / 64.f) - mean * mean;
            const float sc = rsqrtf(var + EPSI);
            const int co = cg * 32 + w * 8 + jj;
            h4[((size_t)(n0 + nn) * 128 + co) * 64 + l] = lrelu((acc[jj][nn] - mean) * sc);
        }
    }
}

// ---------------- K5: FC1 split-K GEMM, partials to workspace --------------------
// C[256,1024] = A[256,8192] x W[1024,8192]^T. BM=BN=64, SK=16 (512 K each), BK=32.
// grid = 64 tiles * 16 sk = 1024 blocks, 256 threads, 4x4 acc/thread.
__global__ __launch_bounds__(256) void k5_fc1(const float* __restrict__ A,
                                              const float* __restrict__ W,
                                              float* __restrict__ Cp) {
    __shared__ float As[32][64];  // [kk][m], m-quad XOR-swizzled
    __shared__ float Bs[32][64];  // [kk][n], n-quad XOR-swizzled
    const int t = threadIdx.x;
    const int sk = blockIdx.x >> 6;
    const int tile = blockIdx.x & 63;
    const int mt = tile >> 4, nt = tile & 15;
    const int m0 = mt * 64, n0 = nt * 64;
    const int tx = t & 15;    // n quad 4*tx
    const int ty = t >> 4;    // m quad 4*ty
    const int lr = t >> 2, lq = t & 3;  // load: row, k-quad
    float acc[4][4] = {};
    const int kbeg = sk * 512;
    for (int k0 = kbeg; k0 < kbeg + 512; k0 += 32) {
        const float4 av0 = *(const float4*)(A + (size_t)(m0 + lr) * 8192 + k0 + 4 * lq);
        const float4 av1 = *(const float4*)(A + (size_t)(m0 + lr) * 8192 + k0 + 16 + 4 * lq);
        const float4 bv0 = *(const float4*)(W + (size_t)(n0 + lr) * 8192 + k0 + 4 * lq);
        const float4 bv1 = *(const float4*)(W + (size_t)(n0 + lr) * 8192 + k0 + 16 + 4 * lq);
        __syncthreads();
        {
            const float a0[4] = {av0.x, av0.y, av0.z, av0.w};
            const float a1[4] = {av1.x, av1.y, av1.z, av1.w};
            const float b0[4] = {bv0.x, bv0.y, bv0.z, bv0.w};
            const float b1[4] = {bv1.x, bv1.y, bv1.z, bv1.w};
            const int q = lr >> 2, r = lr & 3;
            #pragma unroll
            for (int j = 0; j < 4; ++j) {
                const int kkA = 4 * lq + j, kkB = kkA + 16;
                As[kkA][(((q ^ kkA) & 15) << 2) | r] = a0[j];
                As[kkB][(((q ^ kkB) & 15) << 2) | r] = a1[j];
                Bs[kkA][(((q ^ kkA) & 15) << 2) | r] = b0[j];
                Bs[kkB][(((q ^ kkB) & 15) << 2) | r] = b1[j];
            }
        }
        __syncthreads();
        #pragma unroll
        for (int kk = 0; kk < 32; ++kk) {
            const float4 a4 = *(const float4*)&As[kk][((ty ^ kk) & 15) << 2];
            const float4 b4 = *(const float4*)&Bs[kk][((tx ^ kk) & 15) << 2];
            const float a[4] = {a4.x, a4.y, a4.z, a4.w};
            const float b[4] = {b4.x, b4.y, b4.z, b4.w};
            #pragma unroll
            for (int i = 0; i < 4; ++i)
                #pragma unroll
                for (int j = 0; j < 4; ++j)
                    acc[i][j] += a[i] * b[j];
        }
    }
    #pragma unroll
    for (int i = 0; i < 4; ++i) {
        const int m = m0 + 4 * ty + i;
        float4 v = make_float4(acc[i][0], acc[i][1], acc[i][2], acc[i][3]);
        *(float4*)(Cp + ((size_t)sk * 256 + m) * 1024 + n0 + 4 * tx) = v;
    }
}

// ---------------- R5: reduce split-K partials + bias + lrelu ---------------------
__global__ __launch_bounds__(256) void r5_reduce(const float* __restrict__ Cp,
                                                 const float* __restrict__ bias,
                                                 float* __restrict__ h5) {
    const int gid = blockIdx.x * 256 + threadIdx.x;  // 256*1024 total
    const int m = gid >> 10, nn = gid & 1023;
    float s = 0.f;
    #pragma unroll
    for (int sk = 0; sk < 16; ++sk)
        s += Cp[((size_t)sk * 256 + m) * 1024 + nn];
    h5[gid] = lrelu(s + bias[nn]);
}

// ---------------- K6: FC2 [256,1024]x[1,1024]^T + bias ---------------------------
__global__ __launch_bounds__(256) void k6_fc2(const float* __restrict__ h5,
                                              const float* __restrict__ w,
                                              const float* __restrict__ b,
                                              float* __restrict__ out) {
    const int n = blockIdx.x, t = threadIdx.x;
    const float* r = h5 + (size_t)n * 1024;
    float s = 0.f;
    #pragma unroll
    for (int i = 0; i < 4; ++i) s += r[t + 256 * i] * w[t + 256 * i];
    const float2 red = block_reduce_sum2(s, 0.f);
    if (t == 0) out[n] = red.x + b[0];
}

extern "C" void kernel_launch(void* const* d_in, const int* in_sizes, int n_in,
                              void* d_out, int out_size, void* d_ws, size_t ws_size,
                              hipStream_t stream) {
    (void)in_sizes; (void)n_in; (void)out_size; (void)ws_size;
    const float* x    = (const float*)d_in[0];
    // labels (d_in[1]) and conv biases (d_in[3,5,7,9]) cancel exactly under InstanceNorm
    const float* w1   = (const float*)d_in[2];
    const float* w2   = (const float*)d_in[4];
    const float* w3   = (const float*)d_in[6];
    const float* w4   = (const float*)d_in[8];
    const float* fcw1 = (const float*)d_in[10];
    const float* fcb1 = (const float*)d_in[11];
    const float* fcw2 = (const float*)d_in[12];
    const float* fcb2 = (const float*)d_in[13];
    float* out = (float*)d_out;
    float* bufA = (float*)d_ws;          // 16,777,216 floats (67.1 MB)
    float* bufB = bufA + 16777216;       //  8,388,608 floats (33.5 MB)
    float* h1 = bufA;                    // 16.7M floats
    float* h2 = bufB;                    // 8.4M used
    float* h3 = bufA;                    // h1 dead
    float* h4 = bufB;                    // h2 dead
    float* Cp = bufA;                    // h3 dead at k5; 4.2M floats
    float* h5 = bufA + 4194304;          // 262144 floats
    k1_conv_in<<<256, 1024, 0, stream>>>(x, w1, h1);
    k2_conv_in<<<256, 512, 0, stream>>>(h1, w2, h2);
    k3_conv_in<<<512, 256, 0, stream>>>(h2, w3, h3);
    k4_conv_in<<<256, 256, 0, stream>>>(h3, w4, h4);
    k5_fc1<<<1024, 256, 0, stream>>>(h4, fcw1, Cp);
    r5_reduce<<<1024, 256, 0, stream>>>(Cp, fcb1, h5);
    k6_fc2<<<256, 256, 0, stream>>>(h5, fcw2, fcb2, out);
}

// Round 8
// 179.693 us; speedup vs baseline: 2.6817x; 1.2032x over previous
//
#include <hip/hip_runtime.h>

#define EPSI 1e-5f

typedef __attribute__((ext_vector_type(8))) short bf16x8;
typedef __attribute__((ext_vector_type(4))) float f32x4;

__device__ __forceinline__ float lrelu(float x) { return x > 0.f ? x : 0.01f * x; }

// float -> bf16 bits, round-to-nearest-even (header-free)
__device__ __forceinline__ unsigned short f2bf(float x) {
    unsigned int u = __float_as_uint(x);
    return (unsigned short)((u + 0x7fffu + ((u >> 16) & 1u)) >> 16);
}

// Block-wide sum of (a,b). blockDim.x == 256. Result broadcast to all threads.
__device__ __forceinline__ float2 block_reduce_sum2(float a, float b) {
    #pragma unroll
    for (int off = 1; off < 64; off <<= 1) {
        a += __shfl_xor(a, off, 64);
        b += __shfl_xor(b, off, 64);
    }
    __shared__ float lds[8];
    const int t = threadIdx.x;
    if ((t & 63) == 0) { lds[2 * (t >> 6)] = a; lds[2 * (t >> 6) + 1] = b; }
    __syncthreads();
    a = lds[0] + lds[2] + lds[4] + lds[6];
    b = lds[1] + lds[3] + lds[5] + lds[7];
    return make_float2(a, b);
}

// ---------------- K1: conv1(3->16) + IN + lrelu, ALL co per block ----------------
__global__ __launch_bounds__(1024, 1) void k1_conv_in(const float* __restrict__ x,
                                                      const float* __restrict__ w1,
                                                      float* __restrict__ h1) {
    const int n = blockIdx.x;
    const int t = threadIdx.x;
    __shared__ float red[16][16][2]; // [wave][co][s1/s2]
    __shared__ float msc[16][2];     // [co][mean/scale]
    const float* xn = x + (size_t)n * 49152;
    float acc[16][4];
    #pragma unroll
    for (int j = 0; j < 16; ++j)
        #pragma unroll
        for (int q = 0; q < 4; ++q) acc[j][q] = 0.f;
    #pragma unroll 1
    for (int ic = 0; ic < 3; ++ic) {
        const float* p = xn + ic * 16384;
        float2 v0[4], v1[4];
        #pragma unroll
        for (int q = 0; q < 4; ++q) {
            const int idx = t + 1024 * q;
            const int oy = idx >> 6, ox = idx & 63;
            v0[q] = ((const float2*)(p + (2 * oy) * 128))[ox];
            v1[q] = ((const float2*)(p + (2 * oy + 1) * 128))[ox];
        }
        #pragma unroll
        for (int j = 0; j < 16; ++j) {
            const float4 wv = *(const float4*)(w1 + j * 12 + ic * 4);  // uniform -> SGPR
            #pragma unroll
            for (int q = 0; q < 4; ++q)
                acc[j][q] += v0[q].x * wv.x + v0[q].y * wv.y + v1[q].x * wv.z + v1[q].y * wv.w;
        }
    }
    const int w = t >> 6, l = t & 63;
    #pragma unroll
    for (int j = 0; j < 16; ++j) {
        float s1 = acc[j][0] + acc[j][1] + acc[j][2] + acc[j][3];
        float s2 = acc[j][0] * acc[j][0] + acc[j][1] * acc[j][1] +
                   acc[j][2] * acc[j][2] + acc[j][3] * acc[j][3];
        #pragma unroll
        for (int off = 1; off < 64; off <<= 1) {
            s1 += __shfl_xor(s1, off, 64);
            s2 += __shfl_xor(s2, off, 64);
        }
        if (l == 0) { red[w][j][0] = s1; red[w][j][1] = s2; }
    }
    __syncthreads();
    if (t < 16) {
        float s1 = 0.f, s2 = 0.f;
        #pragma unroll
        for (int ww = 0; ww < 16; ++ww) { s1 += red[ww][t][0]; s2 += red[ww][t][1]; }
        const float mean = s1 * (1.f / 4096.f);
        const float var = s2 * (1.f / 4096.f) - mean * mean;
        msc[t][0] = mean; msc[t][1] = rsqrtf(var + EPSI);
    }
    __syncthreads();
    float* on = h1 + (size_t)n * 65536;
    #pragma unroll
    for (int j = 0; j < 16; ++j) {
        const float mean = msc[j][0], sc = msc[j][1];
        #pragma unroll
        for (int q = 0; q < 4; ++q)
            on[j * 4096 + t + 1024 * q] = lrelu((acc[j][q] - mean) * sc);
    }
}

// ---------------- K2: conv2(16->32) + IN + lrelu, ALL co per block ---------------
__global__ __launch_bounds__(512, 2) void k2_conv_in(const float* __restrict__ h1,
                                                     const float* __restrict__ w2,
                                                     float* __restrict__ h2) {
    const int n = blockIdx.x;
    const int t = threadIdx.x;
    __shared__ float red[8][32][2];
    __shared__ float msc[32][2];
    const float* h1n = h1 + (size_t)n * 65536;
    float acc[32][2];
    #pragma unroll
    for (int j = 0; j < 32; ++j) { acc[j][0] = 0.f; acc[j][1] = 0.f; }
    #pragma unroll 1
    for (int ic = 0; ic < 16; ++ic) {
        const float* p = h1n + ic * 4096;
        float2 v0[2], v1[2];
        #pragma unroll
        for (int q = 0; q < 2; ++q) {
            const int idx = t + 512 * q;
            const int oy = idx >> 5, ox = idx & 31;
            v0[q] = ((const float2*)(p + (2 * oy) * 64))[ox];
            v1[q] = ((const float2*)(p + (2 * oy + 1) * 64))[ox];
        }
        #pragma unroll
        for (int j = 0; j < 32; ++j) {
            const float4 wv = *(const float4*)(w2 + j * 144 + ic * 4);  // uniform -> SGPR
            #pragma unroll
            for (int q = 0; q < 2; ++q)
                acc[j][q] += v0[q].x * wv.x + v0[q].y * wv.y + v1[q].x * wv.z + v1[q].y * wv.w;
        }
    }
    const int w = t >> 6, l = t & 63;
    #pragma unroll
    for (int j = 0; j < 32; ++j) {
        float s1 = acc[j][0] + acc[j][1];
        float s2 = acc[j][0] * acc[j][0] + acc[j][1] * acc[j][1];
        #pragma unroll
        for (int off = 1; off < 64; off <<= 1) {
            s1 += __shfl_xor(s1, off, 64);
            s2 += __shfl_xor(s2, off, 64);
        }
        if (l == 0) { red[w][j][0] = s1; red[w][j][1] = s2; }
    }
    __syncthreads();
    if (t < 32) {
        float s1 = 0.f, s2 = 0.f;
        #pragma unroll
        for (int ww = 0; ww < 8; ++ww) { s1 += red[ww][t][0]; s2 += red[ww][t][1]; }
        const float mean = s1 * (1.f / 1024.f);
        const float var = s2 * (1.f / 1024.f) - mean * mean;
        msc[t][0] = mean; msc[t][1] = rsqrtf(var + EPSI);
    }
    __syncthreads();
    float* on = h2 + (size_t)n * 32768;
    #pragma unroll
    for (int j = 0; j < 32; ++j) {
        const float mean = msc[j][0], sc = msc[j][1];
        #pragma unroll
        for (int q = 0; q < 2; ++q)
            on[j * 1024 + t + 512 * q] = lrelu((acc[j][q] - mean) * sc);
    }
}

// ---------------- K3: conv3(32->64) + IN + lrelu, 2n x 16co per block ------------
__global__ __launch_bounds__(256, 2) void k3_conv_in(const float* __restrict__ h2,
                                                     const float* __restrict__ w3,
                                                     float* __restrict__ h3) {
    const int n0 = (blockIdx.x >> 2) * 2, cg = blockIdx.x & 3;
    const int t = threadIdx.x;
    __shared__ float red[4][16][2][2]; // [wave][co][n][s1/s2]
    const int oy = t >> 4, ox = t & 15;
    float acc[16][2];
    #pragma unroll
    for (int j = 0; j < 16; ++j) { acc[j][0] = 0.f; acc[j][1] = 0.f; }
    #pragma unroll 1
    for (int ic = 0; ic < 32; ++ic) {
        float2 v0[2], v1[2];
        #pragma unroll
        for (int nn = 0; nn < 2; ++nn) {
            const float* p = h2 + ((size_t)(n0 + nn) * 32 + ic) * 1024 + (2 * oy) * 32;
            v0[nn] = ((const float2*)p)[ox];
            v1[nn] = ((const float2*)(p + 32))[ox];
        }
        #pragma unroll
        for (int j = 0; j < 16; ++j) {
            const float4 wv = *(const float4*)(w3 + (size_t)(cg * 16 + j) * 128 + ic * 4);
            #pragma unroll
            for (int nn = 0; nn < 2; ++nn)
                acc[j][nn] += v0[nn].x * wv.x + v0[nn].y * wv.y + v1[nn].x * wv.z + v1[nn].y * wv.w;
        }
    }
    const int w = t >> 6, l = t & 63;
    #pragma unroll
    for (int j = 0; j < 16; ++j) {
        #pragma unroll
        for (int nn = 0; nn < 2; ++nn) {
            float s1 = acc[j][nn], s2 = acc[j][nn] * acc[j][nn];
            #pragma unroll
            for (int off = 1; off < 64; off <<= 1) {
                s1 += __shfl_xor(s1, off, 64);
                s2 += __shfl_xor(s2, off, 64);
            }
            if (l == 0) { red[w][j][nn][0] = s1; red[w][j][nn][1] = s2; }
        }
    }
    __syncthreads();
    #pragma unroll
    for (int j = 0; j < 16; ++j) {
        #pragma unroll
        for (int nn = 0; nn < 2; ++nn) {
            const float s1 = red[0][j][nn][0] + red[1][j][nn][0] + red[2][j][nn][0] + red[3][j][nn][0];
            const float s2 = red[0][j][nn][1] + red[1][j][nn][1] + red[2][j][nn][1] + red[3][j][nn][1];
            const float mean = s1 * (1.f / 256.f);
            const float var = s2 * (1.f / 256.f) - mean * mean;
            const float sc = rsqrtf(var + EPSI);
            h3[((size_t)(n0 + nn) * 64 + cg * 16 + j) * 256 + t] = lrelu((acc[j][nn] - mean) * sc);
        }
    }
}

// ---------------- CVT: fcw1 -> bf16 (RNE), 8 elems/thread ------------------------
__global__ __launch_bounds__(256) void cvt_w(const float* __restrict__ W,
                                             unsigned short* __restrict__ Wbf) {
    const int gid = blockIdx.x * 256 + threadIdx.x;   // 4096 blocks -> 1,048,576
    const float4 v0 = ((const float4*)W)[2 * gid];
    const float4 v1 = ((const float4*)W)[2 * gid + 1];
    union { unsigned short u[8]; uint4 q; } p;
    p.u[0] = f2bf(v0.x); p.u[1] = f2bf(v0.y); p.u[2] = f2bf(v0.z); p.u[3] = f2bf(v0.w);
    p.u[4] = f2bf(v1.x); p.u[5] = f2bf(v1.y); p.u[6] = f2bf(v1.z); p.u[7] = f2bf(v1.w);
    ((uint4*)Wbf)[gid] = p.q;
}

// ---------------- K4: conv4(64->128) + IN + lrelu -> bf16 h4 ---------------------
__global__ __launch_bounds__(256, 2) void k4_conv_in(const float* __restrict__ h3,
                                                     const float* __restrict__ w4,
                                                     unsigned short* __restrict__ h4) {
    const int n0 = (blockIdx.x >> 2) * 4, cg = blockIdx.x & 3;
    const int t = threadIdx.x;
    const int w = __builtin_amdgcn_readfirstlane(t >> 6);
    const int l = t & 63;
    const int oy = l >> 3, ox = l & 7;
    const float* wbase = w4 + (size_t)(cg * 32 + w * 8) * 256;
    float acc[8][4];
    #pragma unroll
    for (int jj = 0; jj < 8; ++jj)
        #pragma unroll
        for (int nn = 0; nn < 4; ++nn) acc[jj][nn] = 0.f;
    #pragma unroll 1
    for (int ic = 0; ic < 64; ++ic) {
        float2 v0[4], v1[4];
        #pragma unroll
        for (int nn = 0; nn < 4; ++nn) {
            const float* p = h3 + ((size_t)(n0 + nn) * 64 + ic) * 256 + (2 * oy) * 16;
            v0[nn] = ((const float2*)p)[ox];
            v1[nn] = ((const float2*)(p + 16))[ox];
        }
        #pragma unroll
        for (int jj = 0; jj < 8; ++jj) {
            const float4 wv = *(const float4*)(wbase + jj * 256 + ic * 4);  // wave-uniform -> SGPR
            #pragma unroll
            for (int nn = 0; nn < 4; ++nn)
                acc[jj][nn] += v0[nn].x * wv.x + v0[nn].y * wv.y + v1[nn].x * wv.z + v1[nn].y * wv.w;
        }
    }
    #pragma unroll
    for (int jj = 0; jj < 8; ++jj) {
        #pragma unroll
        for (int nn = 0; nn < 4; ++nn) {
            float s1 = acc[jj][nn], s2 = acc[jj][nn] * acc[jj][nn];
            #pragma unroll
            for (int off = 1; off < 64; off <<= 1) {
                s1 += __shfl_xor(s1, off, 64);
                s2 += __shfl_xor(s2, off, 64);
            }
            const float mean = s1 * (1.f / 64.f);
            const float var = s2 * (1.f / 64.f) - mean * mean;
            const float sc = rsqrtf(var + EPSI);
            const int co = cg * 32 + w * 8 + jj;
            h4[((size_t)(n0 + nn) * 128 + co) * 64 + l] = f2bf(lrelu((acc[jj][nn] - mean) * sc));
        }
    }
}

// ---------------- K5: FC1 bf16 MFMA split-K GEMM ---------------------------------
// C[256,1024] = A[256,8192] x W[1024,8192]^T, both bf16 row-major (TN layout).
// BM=BN=128, BK=64, SK=32 (K-chunk 256): grid = 16 tiles x 32 sk = 512 blocks.
// 4 waves (2x2), wave-tile 64x64 = 4x4 frags of mfma_f32_16x16x32_bf16.
// LDS rows padded to 72 bf16 (144B = 9 x 16B slots): b128 reads/writes spread
// uniformly over bank-quads, 16B-aligned.
__global__ __launch_bounds__(256, 2) void k5_fc1(const unsigned short* __restrict__ A,
                                                 const unsigned short* __restrict__ W,
                                                 float* __restrict__ Cp) {
    __shared__ unsigned short As[128 * 72];
    __shared__ unsigned short Bs[128 * 72];
    const int t = threadIdx.x;
    const int sk = blockIdx.x >> 4;          // 0..31
    const int tile = blockIdx.x & 15;        // mt*8 + nt
    const int mt = tile >> 3, nt = tile & 7;
    const int m0 = mt * 128, n0 = nt * 128;
    const int w = t >> 6, l = t & 63;
    const int wm = (w >> 1) * 64, wn = (w & 1) * 64;
    const int lr16 = l & 15, lk8 = (l >> 4) * 8;   // frag row / k-base (guide §3)
    const int srow = t >> 3, scol = (t & 7) * 8;   // staging row / col
    f32x4 acc[4][4];
    const f32x4 z = {0.f, 0.f, 0.f, 0.f};
    #pragma unroll
    for (int f = 0; f < 4; ++f)
        #pragma unroll
        for (int g = 0; g < 4; ++g) acc[f][g] = z;
    const int kbeg = sk * 256;
    #pragma unroll 1
    for (int kt = 0; kt < 4; ++kt) {
        const int kc = kbeg + kt * 64;
        bf16x8 av[4], bv[4];
        #pragma unroll
        for (int i = 0; i < 4; ++i) {
            av[i] = *(const bf16x8*)(A + (size_t)(m0 + srow + 32 * i) * 8192 + kc + scol);
            bv[i] = *(const bf16x8*)(W + (size_t)(n0 + srow + 32 * i) * 8192 + kc + scol);
        }
        __syncthreads();   // previous tile's frag reads complete
        #pragma unroll
        for (int i = 0; i < 4; ++i) {
            *(bf16x8*)&As[(srow + 32 * i) * 72 + scol] = av[i];
            *(bf16x8*)&Bs[(srow + 32 * i) * 72 + scol] = bv[i];
        }
        __syncthreads();   // tile staged
        #pragma unroll
        for (int ks = 0; ks < 2; ++ks) {
            bf16x8 af[4], bfr[4];
            #pragma unroll
            for (int f = 0; f < 4; ++f)
                af[f] = *(const bf16x8*)&As[(wm + f * 16 + lr16) * 72 + ks * 32 + lk8];
            #pragma unroll
            for (int g = 0; g < 4; ++g)
                bfr[g] = *(const bf16x8*)&Bs[(wn + g * 16 + lr16) * 72 + ks * 32 + lk8];
            #pragma unroll
            for (int f = 0; f < 4; ++f)
                #pragma unroll
                for (int g = 0; g < 4; ++g)
                    acc[f][g] = __builtin_amdgcn_mfma_f32_16x16x32_bf16(af[f], bfr[g], acc[f][g], 0, 0, 0);
        }
    }
    // C/D layout (guide §3, m89-verified): col = l&15, row = (l>>4)*4 + reg
    const int orow = (l >> 4) * 4, ocol = l & 15;
    #pragma unroll
    for (int f = 0; f < 4; ++f) {
        #pragma unroll
        for (int g = 0; g < 4; ++g) {
            #pragma unroll
            for (int j = 0; j < 4; ++j) {
                const int m = m0 + wm + f * 16 + orow + j;
                const int n = n0 + wn + g * 16 + ocol;
                Cp[((size_t)sk * 256 + m) * 1024 + n] = acc[f][g][j];
            }
        }
    }
}

// ---------------- R5: reduce split-K partials + bias + lrelu ---------------------
__global__ __launch_bounds__(256) void r5_reduce(const float* __restrict__ Cp,
                                                 const float* __restrict__ bias,
                                                 float* __restrict__ h5) {
    const int gid = blockIdx.x * 256 + threadIdx.x;  // 256*1024 total
    const int m = gid >> 10, nn = gid & 1023;
    float s = 0.f;
    #pragma unroll
    for (int sk = 0; sk < 32; ++sk)
        s += Cp[((size_t)sk * 256 + m) * 1024 + nn];
    h5[gid] = lrelu(s + bias[nn]);
}

// ---------------- K6: FC2 [256,1024]x[1,1024]^T + bias ---------------------------
__global__ __launch_bounds__(256) void k6_fc2(const float* __restrict__ h5,
                                              const float* __restrict__ w,
                                              const float* __restrict__ b,
                                              float* __restrict__ out) {
    const int n = blockIdx.x, t = threadIdx.x;
    const float* r = h5 + (size_t)n * 1024;
    float s = 0.f;
    #pragma unroll
    for (int i = 0; i < 4; ++i) s += r[t + 256 * i] * w[t + 256 * i];
    const float2 red = block_reduce_sum2(s, 0.f);
    if (t == 0) out[n] = red.x + b[0];
}

extern "C" void kernel_launch(void* const* d_in, const int* in_sizes, int n_in,
                              void* d_out, int out_size, void* d_ws, size_t ws_size,
                              hipStream_t stream) {
    (void)in_sizes; (void)n_in; (void)out_size; (void)ws_size;
    const float* x    = (const float*)d_in[0];
    // labels (d_in[1]) and conv biases (d_in[3,5,7,9]) cancel exactly under InstanceNorm
    const float* w1   = (const float*)d_in[2];
    const float* w2   = (const float*)d_in[4];
    const float* w3   = (const float*)d_in[6];
    const float* w4   = (const float*)d_in[8];
    const float* fcw1 = (const float*)d_in[10];
    const float* fcb1 = (const float*)d_in[11];
    const float* fcw2 = (const float*)d_in[12];
    const float* fcb2 = (const float*)d_in[13];
    float* out = (float*)d_out;
    float* bufA = (float*)d_ws;          // 16,777,216 floats (67.1 MB)
    float* bufB = bufA + 16777216;       //  8,388,608 floats (33.5 MB)
    float* h1 = bufA;                    // 16.7M floats (k1->k2)
    float* h2 = bufB;                    // 8.4M floats  (k2->k3, fills bufB)
    float* h3 = bufA;                    // 4.2M floats  (k3->k4, h1 dead)
    unsigned short* h4bf = (unsigned short*)bufB;        // 2.1M bf16 (k4->k5, h2 dead)
    unsigned short* Wbf  = h4bf + 2097152;               // 8.4M bf16 (cvt->k5)
    float* Cp = bufA;                    // 32*256*1024 = 8.4M floats (h3 dead at k5)
    float* h5 = bufA + 8388608;          // 262144 floats
    k1_conv_in<<<256, 1024, 0, stream>>>(x, w1, h1);
    k2_conv_in<<<256, 512, 0, stream>>>(h1, w2, h2);
    k3_conv_in<<<512, 256, 0, stream>>>(h2, w3, h3);
    cvt_w<<<4096, 256, 0, stream>>>(fcw1, Wbf);          // h2 dead from here
    k4_conv_in<<<256, 256, 0, stream>>>(h3, w4, h4bf);
    k5_fc1<<<512, 256, 0, stream>>>(h4bf, Wbf, Cp);
    r5_reduce<<<1024, 256, 0, stream>>>(Cp, fcb1, h5);
    k6_fc2<<<256, 256, 0, stream>>>(h5, fcw2, fcb2, out);
}